// Round 12
// baseline (219.924 us; speedup 1.0000x reference)
//
#include <hip/hip_runtime.h>
#include <hip/hip_bf16.h>

typedef __bf16 bf16_t;
typedef float f32x4 __attribute__((ext_vector_type(4)));
typedef bf16_t bf16x8 __attribute__((ext_vector_type(8)));
typedef bf16_t bf16x4 __attribute__((ext_vector_type(4)));

#define MFMA16(a, b, c) __builtin_amdgcn_mfma_f32_16x16x32_bf16(a, b, c, 0, 0, 0)

// Q pre-scale: 1/sqrt(64) * log2(e), so softmax uses exp2
#define QSCALE 0.18033688011112042f

__device__ __forceinline__ void gl_lds16(const bf16_t* g, bf16_t* l) {
    __builtin_amdgcn_global_load_lds(
        (const __attribute__((address_space(1))) unsigned int*)g,
        (__attribute__((address_space(3))) unsigned int*)l, 16, 0, 0);
}

__device__ __forceinline__ float fexp2(float x) {
    float y;
    asm("v_exp_f32 %0, %1" : "=v"(y) : "v"(x));
    return y;
}

// ---------------------------------------------------------------------------
// Merged prep: [0,6144) x fp32->bf16; [6144,7872) Wqkv^T; [7872,8448) Wo^T.
// ---------------------------------------------------------------------------
__device__ __forceinline__ void conv_t_body(const float* __restrict__ in,
                                            bf16_t* __restrict__ out,
                                            int R, int C, int bx, int by,
                                            float (*t)[33]) {
    const int tx = threadIdx.x & 31;
    const int ty = threadIdx.x >> 5;
#pragma unroll
    for (int i = 0; i < 4; i++)
        t[ty + i * 8][tx] = in[(size_t)(by + ty + i * 8) * C + bx + tx];
    __syncthreads();
#pragma unroll
    for (int i = 0; i < 4; i++)
        out[(size_t)(bx + ty + i * 8) * R + by + tx] = (bf16_t)t[tx][ty + i * 8];
}

__global__ __launch_bounds__(256) void prep_k(
    const float* __restrict__ x,    bf16_t* __restrict__ xb,
    const float* __restrict__ Wqkv, bf16_t* __restrict__ Wt,
    const float* __restrict__ Wo,   bf16_t* __restrict__ Wot)
{
    __shared__ float t[32][33];
    const int blk = blockIdx.x;
    if (blk < 6144) {
        const int i = (blk * 256 + threadIdx.x) * 4;
        float4 v = *(const float4*)(x + i);
        bf16x4 o = { (bf16_t)v.x, (bf16_t)v.y, (bf16_t)v.z, (bf16_t)v.w };
        *(bf16x4*)(xb + i) = o;
    } else if (blk < 7872) {
        const int idx = blk - 6144;
        conv_t_body(Wqkv, Wt, 768, 2304, (idx % 72) * 32, (idx / 72) * 32, t);
    } else {
        const int idx = blk - 7872;
        conv_t_body(Wo, Wot, 768, 768, (idx % 24) * 32, (idx / 24) * 32, t);
    }
}

// ---------------------------------------------------------------------------
// V transpose: Vp [bh][2048][64] -> Vt [bh][64][2048].
// ---------------------------------------------------------------------------
__global__ __launch_bounds__(256) void vtrans(const bf16_t* __restrict__ Vp,
                                              bf16_t* __restrict__ Vt) {
    __shared__ __align__(16) bf16_t Ts[64 * 72];
    const int t0 = blockIdx.x * 64;
    const int bh = blockIdx.y;
    const int r  = threadIdx.x >> 2;
    const int cb = (threadIdx.x & 3) * 16;
    const bf16_t* src = Vp + (((size_t)bh * 2048 + t0 + r) << 6) + cb;
    *(bf16x8*)(Ts + r * 72 + cb)     = *(const bf16x8*)(src);
    *(bf16x8*)(Ts + r * 72 + cb + 8) = *(const bf16x8*)(src + 8);
    __syncthreads();
    const int f  = threadIdx.x >> 2;
    const int tb = (threadIdx.x & 3) * 16;
    bf16_t* dst = Vt + (((size_t)bh * 64 + f) << 11) + t0 + tb;
    bf16x8 a, b;
#pragma unroll
    for (int i = 0; i < 8; i++) a[i] = Ts[(tb + i) * 72 + f];
#pragma unroll
    for (int i = 0; i < 8; i++) b[i] = Ts[(tb + 8 + i) * 72 + f];
    *(bf16x8*)(dst)     = a;
    *(bf16x8*)(dst + 8) = b;
}

// ---------------------------------------------------------------------------
// 256x128 bf16 GEMM, 256 threads = 4 waves in 2x2, wave tile 128x64 (acc
// 8x4): 12 ds_read_b128 per 32 MFMA per wave (MFMA-bound ratio) while
// keeping 4-wave blocks -> 2 blocks/CU = 8 waves/CU (R11's 128-thread
// variant collapsed to 1 wave/SIMD and was latency-bound).
// BK=32, dbuf, single barrier per K-step, XCD swizzle, XOR bank swizzle.
// ---------------------------------------------------------------------------
template <int EPI>
__global__ __launch_bounds__(256, 2) void gemm_bt(
    const bf16_t* __restrict__ A, const bf16_t* __restrict__ Bt,
    const float* __restrict__ bias,
    void* __restrict__ O0v, bf16_t* __restrict__ O1, bf16_t* __restrict__ O2,
    int M, int N, int K)
{
    __shared__ __align__(16) bf16_t As[2][256 * 32];   // 16 KB x2
    __shared__ __align__(16) bf16_t Bs[2][128 * 32];   //  8 KB x2

    const int tid  = threadIdx.x;
    const int wid  = tid >> 6;
    const int lane = tid & 63;
    const int quad = lane >> 4;
    const int l15  = lane & 15;
    const int wm   = (wid >> 1) * 128;
    const int wn   = (wid & 1) * 64;
    const int qs8  = (quad ^ ((l15 >> 1) & 3)) * 8;   // swizzled colblk

    const int mtiles = M >> 8;            // 256-row tiles
    const int mtpx   = mtiles >> 3;
    const int bid    = blockIdx.x;
    const int xcd    = bid & 7;
    const int slot   = bid >> 3;
    const int m0     = (xcd * mtpx + (slot % mtpx)) << 8;
    const int n0     = (slot / mtpx) << 7;

    f32x4 acc[8][4];
#pragma unroll
    for (int i = 0; i < 8; i++)
#pragma unroll
        for (int j = 0; j < 4; j++) acc[i][j] = (f32x4){0.f, 0.f, 0.f, 0.f};

    const int srow = tid >> 2;                              // 0..63
    const int scol = (((tid & 3) ^ ((srow >> 1) & 3))) * 8; // swizzled src col

    auto prefetch = [&](int k0, int buf) {
#pragma unroll
        for (int s = 0; s < 4; s++)
            gl_lds16(A + (size_t)(m0 + s * 64 + srow) * K + k0 + scol,
                     As[buf] + s * 2048 + tid * 8);
#pragma unroll
        for (int s = 0; s < 2; s++)
            gl_lds16(Bt + (size_t)(n0 + s * 64 + srow) * K + k0 + scol,
                     Bs[buf] + s * 2048 + tid * 8);
    };

    const int niter = K >> 5;
    prefetch(0, 0);
    for (int i = 0; i < niter; i++) {
        __syncthreads();                   // drains prefetch(i); buf i-1 reads done
        if (i + 1 < niter) prefetch((i + 1) << 5, (i + 1) & 1);
        const bf16_t* Ap = As[i & 1];
        const bf16_t* Bp = Bs[i & 1];

        bf16x8 af[8], bfr[4];
#pragma unroll
        for (int ii = 0; ii < 8; ii++)
            af[ii] = *(const bf16x8*)(Ap + (wm + ii * 16 + l15) * 32 + qs8);
#pragma unroll
        for (int j = 0; j < 4; j++)
            bfr[j] = *(const bf16x8*)(Bp + (wn + j * 16 + l15) * 32 + qs8);
#pragma unroll
        for (int ii = 0; ii < 8; ii++)
#pragma unroll
            for (int j = 0; j < 4; j++)
                acc[ii][j] = MFMA16(af[ii], bfr[j], acc[ii][j]);
    }

    if (EPI == 0) {
        const int sec = n0 / 768;              // block-uniform
        const float scale = (sec == 0) ? QSCALE : 1.f;
        bf16_t* dst = (sec == 0) ? (bf16_t*)O0v : (sec == 1 ? O1 : O2);
#pragma unroll
        for (int ii = 0; ii < 8; ii++) {
            const int mbase = m0 + wm + ii * 16 + quad * 4;
#pragma unroll
            for (int j = 0; j < 4; j++) {
                const int n  = n0 + wn + j * 16 + l15;
                const float bv = bias[n];
                const int d    = n - sec * 768;
                const int h    = d >> 6;
                const int feat = d & 63;
#pragma unroll
                for (int r = 0; r < 4; r++) {
                    const int mm = mbase + r;
                    const int b  = mm >> 11;
                    const int tt = mm & 2047;
                    const int bh = b * 12 + h;
                    dst[(((size_t)bh * 2048 + tt) << 6) + feat] =
                        (bf16_t)((acc[ii][j][r] + bv) * scale);
                }
            }
        }
    } else {
#pragma unroll
        for (int ii = 0; ii < 8; ii++) {
            const int mbase = m0 + wm + ii * 16 + quad * 4;
#pragma unroll
            for (int j = 0; j < 4; j++) {
                const int n  = n0 + wn + j * 16 + l15;
                const float bv = bias[n];
#pragma unroll
                for (int r = 0; r < 4; r++)
                    ((float*)O0v)[(size_t)(mbase + r) * N + n] = acc[ii][j][r] + bv;
            }
        }
    }
}

// ---------------------------------------------------------------------------
// Flash attention, causal.  Q-tile 128/block, 4 waves x 32 q (two 16-q
// column groups), LPT grid, XCD swizzle, S^T form, dbuf DMA staging, XOR
// bank swizzle (unchanged from R11).
// ---------------------------------------------------------------------------
__global__ __launch_bounds__(256) void attn_k(
    const bf16_t* __restrict__ Q, const bf16_t* __restrict__ Kb,
    const bf16_t* __restrict__ Vt, bf16_t* __restrict__ AO)
{
    __shared__ __align__(16) bf16_t Ks[2 * 4096];
    __shared__ __align__(16) bf16_t Vs[2 * 4096];
    __shared__ __align__(16) bf16_t Ps[4 * 2048];

    const int tid  = threadIdx.x;
    const int wid  = tid >> 6;
    const int lane = tid & 63;
    const int quad = lane >> 4;
    const int l15  = lane & 15;
    const int qs8  = (quad ^ ((l15 >> 1) & 3)) * 8;

    const int bid  = blockIdx.x;
    const int xcd  = bid & 7;
    const int rank = bid >> 3;                 // 0..95
    const int qi   = 15 - rank / 6;            // largest first (LPT)
    const int bh   = xcd * 6 + (rank % 6);
    const int q0   = qi << 7;

    const bf16_t* Qb  = Q  + ((size_t)bh << 17);
    const bf16_t* Kbh = Kb + ((size_t)bh << 17);
    const bf16_t* Vbh = Vt + ((size_t)bh << 17);

    bf16_t* Pw = Ps + wid * 2048;
    const int swl = l15 & 7;
    bf16_t* pwr[4];
#pragma unroll
    for (int c = 0; c < 4; c++)
        pwr[c] = Pw + l15 * 64 + (((((c << 1) | (quad >> 1))) ^ swl) << 3) + ((quad & 1) << 2);
    const bf16_t* prd[2];
#pragma unroll
    for (int kk = 0; kk < 2; kk++)
        prd[kk] = Pw + l15 * 64 + ((((kk << 2) | quad) ^ swl) << 3);

    const bf16x8 ones = { (bf16_t)1.f, (bf16_t)1.f, (bf16_t)1.f, (bf16_t)1.f,
                          (bf16_t)1.f, (bf16_t)1.f, (bf16_t)1.f, (bf16_t)1.f };

    const int srow = tid >> 2;
    const int scol = (((tid & 3) ^ ((srow >> 1) & 3))) * 8;

    auto prefetch = [&](int j, int buf) {
        const int kv0 = j * 64;
        bf16_t* kd = Ks + buf * 4096 + tid * 8;
        bf16_t* vd = Vs + buf * 4096 + tid * 8;
#pragma unroll
        for (int c = 0; c < 2; c++) {
            gl_lds16(Kbh + (size_t)(kv0 + srow) * 64 + c * 32 + scol, kd + c * 2048);
            gl_lds16(Vbh + (size_t)srow * 2048 + kv0 + c * 32 + scol, vd + c * 2048);
        }
    };

    const int b = bh / 12;
    const int h = bh - b * 12;

    const int qw0 = q0 + wid * 32;
    const int qwave_max = qw0 + 31;

    bf16x8 qf[2][2];
#pragma unroll
    for (int g = 0; g < 2; g++) {
        const bf16_t* qp = Qb + ((size_t)(qw0 + g * 16 + l15) << 6) + quad * 8;
        qf[g][0] = *(const bf16x8*)(qp);
        qf[g][1] = *(const bf16x8*)(qp + 32);
    }

    f32x4 lacc[2];
    f32x4 oacc[2][4];
#pragma unroll
    for (int g = 0; g < 2; g++) {
        lacc[g] = (f32x4){0.f, 0.f, 0.f, 0.f};
#pragma unroll
        for (int f = 0; f < 4; f++) oacc[g][f] = (f32x4){0.f, 0.f, 0.f, 0.f};
    }

    const int cnt = 2 * qi + 2;
    prefetch(0, 0);

    for (int i = 0; i < cnt; i++) {
        __syncthreads();
        if (i + 1 < cnt) prefetch(i + 1, (i + 1) & 1);
        const int kv0 = i * 64;
        if (kv0 > qwave_max) continue;     // fully masked for this wave
        const bf16_t* Kp = Ks + (i & 1) * 4096;
        const bf16_t* Vp = Vs + (i & 1) * 4096;

        f32x4 st[2][4];
#pragma unroll
        for (int c = 0; c < 4; c++) {
            bf16x8 kf0 = *(const bf16x8*)(Kp + (c * 16 + l15) * 32 + qs8);
            bf16x8 kf1 = *(const bf16x8*)(Kp + 2048 + (c * 16 + l15) * 32 + qs8);
#pragma unroll
            for (int g = 0; g < 2; g++) {
                f32x4 z = (f32x4){0.f, 0.f, 0.f, 0.f};
                z = MFMA16(kf0, qf[g][0], z);
                st[g][c] = MFMA16(kf1, qf[g][1], z);
            }
        }

        if (kv0 + 63 > qw0) {
#pragma unroll
            for (int g = 0; g < 2; g++) {
                const int qg = qw0 + g * 16 + l15;
#pragma unroll
                for (int c = 0; c < 4; c++) {
                    const int kvb = kv0 + c * 16 + quad * 4;
#pragma unroll
                    for (int r = 0; r < 4; r++)
                        if (kvb + r > qg) st[g][c][r] = -3e38f;
                }
            }
        }

#pragma unroll
        for (int g = 0; g < 2; g++)
#pragma unroll
            for (int c = 0; c < 4; c++) {
                bf16x4 pk = { (bf16_t)fexp2(st[g][c][0]), (bf16_t)fexp2(st[g][c][1]),
                              (bf16_t)fexp2(st[g][c][2]), (bf16_t)fexp2(st[g][c][3]) };
                *(bf16x4*)(pwr[c] + g * 1024) = pk;
            }

        bf16x8 pb[2][2];
#pragma unroll
        for (int g = 0; g < 2; g++)
#pragma unroll
            for (int kk = 0; kk < 2; kk++)
                pb[g][kk] = *(const bf16x8*)(prd[kk] + g * 1024);

#pragma unroll
        for (int g = 0; g < 2; g++) {
            lacc[g] = MFMA16(ones, pb[g][0], lacc[g]);
            lacc[g] = MFMA16(ones, pb[g][1], lacc[g]);
        }

#pragma unroll
        for (int f = 0; f < 4; f++) {
            bf16x8 vf0 = *(const bf16x8*)(Vp + (f * 16 + l15) * 32 + qs8);
            bf16x8 vf1 = *(const bf16x8*)(Vp + 2048 + (f * 16 + l15) * 32 + qs8);
#pragma unroll
            for (int g = 0; g < 2; g++) {
                oacc[g][f] = MFMA16(vf0, pb[g][0], oacc[g][f]);
                oacc[g][f] = MFMA16(vf1, pb[g][1], oacc[g][f]);
            }
        }
    }

    // Epilogue: normalize in-register (l lane-local) -> bf16 AO
#pragma unroll
    for (int g = 0; g < 2; g++) {
        const int qg = qw0 + g * 16 + l15;
        const float inv = 1.0f / lacc[g][0];
        bf16_t* dst = AO + ((size_t)(b * 2048 + qg)) * 768 + h * 64 + quad * 4;
#pragma unroll
        for (int f = 0; f < 4; f++) {
            bf16x4 o = { (bf16_t)(oacc[g][f][0] * inv), (bf16_t)(oacc[g][f][1] * inv),
                         (bf16_t)(oacc[g][f][2] * inv), (bf16_t)(oacc[g][f][3] * inv) };
            *(bf16x4*)(dst + f * 16) = o;
        }
    }
}

// ---------------------------------------------------------------------------
extern "C" void kernel_launch(void* const* d_in, const int* in_sizes, int n_in,
                              void* d_out, int out_size, void* d_ws, size_t ws_size,
                              hipStream_t stream)
{
    const float* x    = (const float*)d_in[0];  // [4,2048,768]
    const float* Wqkv = (const float*)d_in[1];  // [768,2304]
    const float* bqkv = (const float*)d_in[2];  // [2304]
    const float* Wo   = (const float*)d_in[3];  // [768,768]
    const float* bo   = (const float*)d_in[4];  // [768]
    float* out = (float*)d_out;                 // [4,2048,768] fp32

    const size_t per = (size_t)48 * 2048 * 64;  // 6291456 bf16 elems
    bf16_t* Qs  = (bf16_t*)d_ws;                // [bh][t][64], pre-scaled
    bf16_t* Kk  = Qs + per;                     // [bh][t][64]
    bf16_t* Vt  = Kk + per;                     // [bh][64][t]
    bf16_t* AO  = Vt + per;                     // [8192,768] bf16
    bf16_t* xb  = AO + per;                     // [8192,768] bf16
    bf16_t* Wt  = xb + per;                     // [2304,768] = Wqkv^T bf16
    bf16_t* Wot = Wt + (size_t)2304 * 768;      // [768,768]  = Wo^T bf16
    bf16_t* Vpl = (bf16_t*)d_out;               // V plain parked in out

    // 0) merged precision/layout conversions
    prep_k<<<8448, 256, 0, stream>>>(x, xb, Wqkv, Wt, Wo, Wot);

    // 1) QKV projection (256x128 block tile, 128x64 wave tile)
    gemm_bt<0><<<576, 256, 0, stream>>>(
        xb, Wt, bqkv, (void*)Qs, Kk, Vpl, 8192, 2304, 768);
    // 1b) V transpose -> Vt [bh][64][t]
    vtrans<<<dim3(32, 48), 256, 0, stream>>>(Vpl, Vt);
    // 2) causal flash attention, Q-tile 128, LPT grid -> normalized AO
    attn_k<<<768, 256, 0, stream>>>(Qs, Kk, Vt, AO);
    // 3) output projection (fp32 out)
    gemm_bt<1><<<192, 256, 0, stream>>>(
        AO, Wot, bo, (void*)out, nullptr, nullptr, 8192, 768, 768);
}

// Round 13
// 207.888 us; speedup vs baseline: 1.0579x; 1.0579x over previous
//
#include <hip/hip_runtime.h>
#include <hip/hip_bf16.h>

typedef __bf16 bf16_t;
typedef float f32x4 __attribute__((ext_vector_type(4)));
typedef bf16_t bf16x8 __attribute__((ext_vector_type(8)));
typedef bf16_t bf16x4 __attribute__((ext_vector_type(4)));

#define MFMA16(a, b, c) __builtin_amdgcn_mfma_f32_16x16x32_bf16(a, b, c, 0, 0, 0)

// Q pre-scale: 1/sqrt(64) * log2(e), so softmax uses exp2
#define QSCALE 0.18033688011112042f

__device__ __forceinline__ void gl_lds16(const bf16_t* g, bf16_t* l) {
    __builtin_amdgcn_global_load_lds(
        (const __attribute__((address_space(1))) unsigned int*)g,
        (__attribute__((address_space(3))) unsigned int*)l, 16, 0, 0);
}

__device__ __forceinline__ float fexp2(float x) {
    float y;
    asm("v_exp_f32 %0, %1" : "=v"(y) : "v"(x));
    return y;
}

// ---------------------------------------------------------------------------
// Merged prep: [0,6144) x fp32->bf16; [6144,7872) Wqkv^T; [7872,8448) Wo^T.
// ---------------------------------------------------------------------------
__device__ __forceinline__ void conv_t_body(const float* __restrict__ in,
                                            bf16_t* __restrict__ out,
                                            int R, int C, int bx, int by,
                                            float (*t)[33]) {
    const int tx = threadIdx.x & 31;
    const int ty = threadIdx.x >> 5;
#pragma unroll
    for (int i = 0; i < 4; i++)
        t[ty + i * 8][tx] = in[(size_t)(by + ty + i * 8) * C + bx + tx];
    __syncthreads();
#pragma unroll
    for (int i = 0; i < 4; i++)
        out[(size_t)(bx + ty + i * 8) * R + by + tx] = (bf16_t)t[tx][ty + i * 8];
}

__global__ __launch_bounds__(256) void prep_k(
    const float* __restrict__ x,    bf16_t* __restrict__ xb,
    const float* __restrict__ Wqkv, bf16_t* __restrict__ Wt,
    const float* __restrict__ Wo,   bf16_t* __restrict__ Wot)
{
    __shared__ float t[32][33];
    const int blk = blockIdx.x;
    if (blk < 6144) {
        const int i = (blk * 256 + threadIdx.x) * 4;
        float4 v = *(const float4*)(x + i);
        bf16x4 o = { (bf16_t)v.x, (bf16_t)v.y, (bf16_t)v.z, (bf16_t)v.w };
        *(bf16x4*)(xb + i) = o;
    } else if (blk < 7872) {
        const int idx = blk - 6144;
        conv_t_body(Wqkv, Wt, 768, 2304, (idx % 72) * 32, (idx / 72) * 32, t);
    } else {
        const int idx = blk - 7872;
        conv_t_body(Wo, Wot, 768, 768, (idx % 24) * 32, (idx / 24) * 32, t);
    }
}

// ---------------------------------------------------------------------------
// 128x128 bf16 GEMM, BK=32, dbuf, single barrier per K-step, XCD swizzle,
// XOR bank swizzle (the R10 champion config: 4 waves of 64x64, 3 blocks/CU).
// EPI=0 QKV epilogue:
//   sec 0/1 (Q,K): coalesced [bh][t][64] scalar stores (as R10).
//   sec 2  (V):   NEW — C-tile routed through the dead As/Bs LDS as
//                 [feat][t] with 16B XOR swizzle, then b128 coalesced
//                 stores directly into Vt [bh][64][t]  (vtrans fused away).
// EPI=1: fp32 C + bias.
// ---------------------------------------------------------------------------
template <int EPI>
__global__ __launch_bounds__(256) void gemm_bt(
    const bf16_t* __restrict__ A, const bf16_t* __restrict__ Bt,
    const float* __restrict__ bias,
    void* __restrict__ O0v, bf16_t* __restrict__ O1, bf16_t* __restrict__ O2,
    int M, int N, int K)
{
    __shared__ __align__(16) bf16_t As[2][128 * 32];
    __shared__ __align__(16) bf16_t Bs[2][128 * 32];

    const int tid  = threadIdx.x;
    const int wid  = tid >> 6;
    const int lane = tid & 63;
    const int quad = lane >> 4;
    const int l15  = lane & 15;
    const int wm   = (wid >> 1) * 64;
    const int wn   = (wid & 1) * 64;
    const int qs8  = (quad ^ ((l15 >> 1) & 3)) * 8;   // swizzled colblk

    const int mtiles = M >> 7;
    const int mtpx   = mtiles >> 3;
    const int bid    = blockIdx.x;
    const int xcd    = bid & 7;
    const int slot   = bid >> 3;
    const int m0     = (xcd * mtpx + (slot % mtpx)) << 7;
    const int n0     = (slot / mtpx) << 7;

    f32x4 acc[4][4];
#pragma unroll
    for (int i = 0; i < 4; i++)
#pragma unroll
        for (int j = 0; j < 4; j++) acc[i][j] = (f32x4){0.f, 0.f, 0.f, 0.f};

    const int srow = tid >> 2;
    const int scol = (((tid & 3) ^ ((srow >> 1) & 3))) * 8;   // swizzled src col
    const bf16_t* ag0 = A  + (size_t)(m0 + srow) * K + scol;
    const bf16_t* ag1 = A  + (size_t)(m0 + 64 + srow) * K + scol;
    const bf16_t* bg0 = Bt + (size_t)(n0 + srow) * K + scol;
    const bf16_t* bg1 = Bt + (size_t)(n0 + 64 + srow) * K + scol;

    auto prefetch = [&](int k0, int buf) {
        gl_lds16(ag0 + k0, As[buf] + tid * 8);
        gl_lds16(ag1 + k0, As[buf] + 2048 + tid * 8);
        gl_lds16(bg0 + k0, Bs[buf] + tid * 8);
        gl_lds16(bg1 + k0, Bs[buf] + 2048 + tid * 8);
    };

    const int niter = K >> 5;
    prefetch(0, 0);
    for (int i = 0; i < niter; i++) {
        __syncthreads();
        if (i + 1 < niter) prefetch((i + 1) << 5, (i + 1) & 1);
        const bf16_t* Ap = As[i & 1];
        const bf16_t* Bp = Bs[i & 1];

        bf16x8 af[4], bfr[4];
#pragma unroll
        for (int ii = 0; ii < 4; ii++)
            af[ii] = *(const bf16x8*)(Ap + (wm + ii * 16 + l15) * 32 + qs8);
#pragma unroll
        for (int j = 0; j < 4; j++)
            bfr[j] = *(const bf16x8*)(Bp + (wn + j * 16 + l15) * 32 + qs8);
#pragma unroll
        for (int ii = 0; ii < 4; ii++)
#pragma unroll
            for (int j = 0; j < 4; j++)
                acc[ii][j] = MFMA16(af[ii], bfr[j], acc[ii][j]);
    }

    if (EPI == 0) {
        const int sec = n0 / 768;              // block-uniform
        if (sec < 2) {
            // Q / K: coalesced [bh][t][64] scalar stores (R10 path)
            const float scale = (sec == 0) ? QSCALE : 1.f;
            bf16_t* dst = (sec == 0) ? (bf16_t*)O0v : O1;
#pragma unroll
            for (int i = 0; i < 4; i++) {
                const int mbase = m0 + wm + i * 16 + quad * 4;
#pragma unroll
                for (int j = 0; j < 4; j++) {
                    const int n  = n0 + wn + j * 16 + l15;
                    const float bv = bias[n];
                    const int d    = n - sec * 768;
                    const int h    = d >> 6;
                    const int feat = d & 63;
#pragma unroll
                    for (int r = 0; r < 4; r++) {
                        const int mm = mbase + r;
                        const int b  = mm >> 11;
                        const int tt = mm & 2047;
                        const int bh = b * 12 + h;
                        dst[(((size_t)bh * 2048 + tt) << 6) + feat] =
                            (bf16_t)((acc[i][j][r] + bv) * scale);
                    }
                }
            }
        } else {
            // V: transpose through reused As/Bs LDS -> Vt [bh][64][t]
            __syncthreads();                   // all waves done with K-loop LDS
            bf16_t* H = (wid & 1) ? (bf16_t*)Bs[0] : (bf16_t*)As[0];  // per-head 64x128
            // Write phase: (t = wm+i*16+quad*4+r, f = j*16+l15); r walks t ->
            // one b64 per (i,j).  16B-unit XOR swizzle keyed by f&15 (= l15).
#pragma unroll
            for (int i = 0; i < 4; i++) {
                const int tb   = wm + i * 16 + quad * 4;
                const int ut   = tb >> 3;
                const int half = (tb >> 2) & 1;
#pragma unroll
                for (int j = 0; j < 4; j++) {
                    const int f = j * 16 + l15;
                    const float bv = bias[n0 + wn + f];
                    bf16x4 v = { (bf16_t)(acc[i][j][0] + bv), (bf16_t)(acc[i][j][1] + bv),
                                 (bf16_t)(acc[i][j][2] + bv), (bf16_t)(acc[i][j][3] + bv) };
                    *(bf16x4*)(H + f * 128 + ((ut ^ l15) << 3) + half * 4) = v;
                }
            }
            __syncthreads();
            // Read phase: b128 per (f, 8-t unit), coalesced b128 global stores
            const int b   = m0 >> 11;
            const int t0  = m0 & 2047;
            const int h0  = (n0 - 1536) >> 6;
            const int bh  = b * 12 + h0 + (wid & 1);
            const int p   = ((wid >> 1) << 6) | lane;   // 0..127 within head
            const int utr = p & 15;
#pragma unroll
            for (int rr = 0; rr < 8; rr++) {
                const int f = (p >> 4) + rr * 8;
                bf16x8 v = *(const bf16x8*)(H + f * 128 + ((utr ^ (f & 15)) << 3));
                *(bf16x8*)(O2 + (((size_t)bh * 64 + f) << 11) + t0 + utr * 8) = v;
            }
        }
    } else {
#pragma unroll
        for (int i = 0; i < 4; i++) {
            const int mbase = m0 + wm + i * 16 + quad * 4;
#pragma unroll
            for (int j = 0; j < 4; j++) {
                const int n  = n0 + wn + j * 16 + l15;
                const float bv = bias[n];
#pragma unroll
                for (int r = 0; r < 4; r++)
                    ((float*)O0v)[(size_t)(mbase + r) * N + n] = acc[i][j][r] + bv;
            }
        }
    }
}

// ---------------------------------------------------------------------------
// Flash attention, causal, non-split, S^T form, dbuf DMA staging, XCD
// swizzle, XOR bank swizzle — the R10 champion version (64-q paired blocks,
// every block exactly 33 KV tiles, 768 blocks = 3/CU, zero tail).
// ---------------------------------------------------------------------------
__global__ __launch_bounds__(256) void attn_k(
    const bf16_t* __restrict__ Q, const bf16_t* __restrict__ Kb,
    const bf16_t* __restrict__ Vt, bf16_t* __restrict__ AO)
{
    __shared__ __align__(16) bf16_t Ks[2 * 4096];   // [buf][kk][kv64][feat32] swz
    __shared__ __align__(16) bf16_t Vs[2 * 4096];   // [buf][kk][feat64][kv32] swz
    __shared__ __align__(16) bf16_t Ps[4 * 1024];

    const int tid  = threadIdx.x;
    const int wid  = tid >> 6;
    const int lane = tid & 63;
    const int quad = lane >> 4;
    const int l15  = lane & 15;
    const int qs8  = (quad ^ ((l15 >> 1) & 3)) * 8;

    // XCD decode: 768 blocks = 8 xcd x (6 bh x 16 pairs)
    const int bid  = blockIdx.x;
    const int xcd  = bid & 7;
    const int slot = bid >> 3;
    const int bh   = xcd * 6 + (slot >> 4);
    const int p    = slot & 15;

    const bf16_t* Qb  = Q  + ((size_t)bh << 17);
    const bf16_t* Kbh = Kb + ((size_t)bh << 17);
    const bf16_t* Vbh = Vt + ((size_t)bh << 17);

    bf16_t* Pw = Ps + wid * 1024;
    const int swl = l15 & 7;
    bf16_t* pwr[4];
#pragma unroll
    for (int c = 0; c < 4; c++)
        pwr[c] = Pw + l15 * 64 + (((((c << 1) | (quad >> 1))) ^ swl) << 3) + ((quad & 1) << 2);
    const bf16_t* prd[2];
#pragma unroll
    for (int kk = 0; kk < 2; kk++)
        prd[kk] = Pw + l15 * 64 + ((((kk << 2) | quad) ^ swl) << 3);

    const bf16x8 ones = { (bf16_t)1.f, (bf16_t)1.f, (bf16_t)1.f, (bf16_t)1.f,
                          (bf16_t)1.f, (bf16_t)1.f, (bf16_t)1.f, (bf16_t)1.f };

    const int srow = tid >> 2;
    const int scol = (((tid & 3) ^ ((srow >> 1) & 3))) * 8;

    auto prefetch = [&](int j, int buf) {
        const int kv0 = j * 64;
        bf16_t* kd = Ks + buf * 4096 + tid * 8;
        bf16_t* vd = Vs + buf * 4096 + tid * 8;
#pragma unroll
        for (int c = 0; c < 2; c++) {
            gl_lds16(Kbh + (size_t)(kv0 + srow) * 64 + c * 32 + scol, kd + c * 2048);
            gl_lds16(Vbh + (size_t)srow * 2048 + kv0 + c * 32 + scol, vd + c * 2048);
        }
    };

    const int b = bh / 12;
    const int h = bh - b * 12;

#pragma unroll
    for (int half = 0; half < 2; half++) {
        const int qt = half == 0 ? (31 - p) : p;
        const int q0 = qt * 64;
        const int qg = q0 + wid * 16 + l15;

        bf16x8 qf[2];
        {
            const bf16_t* qp = Qb + ((size_t)qg << 6) + quad * 8;
            qf[0] = *(const bf16x8*)(qp);
            qf[1] = *(const bf16x8*)(qp + 32);
        }

        f32x4 lacc = (f32x4){0.f, 0.f, 0.f, 0.f};
        f32x4 oacc[4];
#pragma unroll
        for (int f = 0; f < 4; f++) oacc[f] = (f32x4){0.f, 0.f, 0.f, 0.f};

        const int cnt = qt + 1;
        prefetch(0, 0);

        for (int i = 0; i < cnt; i++) {
            __syncthreads();                   // drains prefetch from iter i-1
            if (i + 1 < cnt) prefetch(i + 1, (i + 1) & 1);
            const bf16_t* Kp = Ks + (i & 1) * 4096;
            const bf16_t* Vp = Vs + (i & 1) * 4096;

            // S^T = K Q^T (C-layout: row = kv = quad*4+r, col = q = l15)
            f32x4 st[4];
#pragma unroll
            for (int c = 0; c < 4; c++) {
                st[c] = (f32x4){0.f, 0.f, 0.f, 0.f};
#pragma unroll
                for (int kk = 0; kk < 2; kk++) {
                    bf16x8 kf = *(const bf16x8*)(Kp + kk * 2048 + (c * 16 + l15) * 32 + qs8);
                    st[c] = MFMA16(kf, qf[kk], st[c]);
                }
            }

            // Causal mask only on the diagonal tile
            if (i == qt) {
                const int kvb = q0 + quad * 4;
#pragma unroll
                for (int c = 0; c < 4; c++)
#pragma unroll
                    for (int r = 0; r < 4; r++)
                        if (kvb + c * 16 + r > qg) st[c][r] = -3e38f;
            }

            // P^T = exp2(S^T): one b64 LDS write per c
#pragma unroll
            for (int c = 0; c < 4; c++) {
                bf16x4 pk = { (bf16_t)fexp2(st[c][0]), (bf16_t)fexp2(st[c][1]),
                              (bf16_t)fexp2(st[c][2]), (bf16_t)fexp2(st[c][3]) };
                *(bf16x4*)pwr[c] = pk;
            }

            bf16x8 pb[2];
#pragma unroll
            for (int kk = 0; kk < 2; kk++)
                pb[kk] = *(const bf16x8*)prd[kk];

            // l[q] += colsum(P^T): lands at col=l15 (lane-local)
            lacc = MFMA16(ones, pb[0], lacc);
            lacc = MFMA16(ones, pb[1], lacc);

            // O^T += V^T P^T
#pragma unroll
            for (int f = 0; f < 4; f++)
#pragma unroll
                for (int kk = 0; kk < 2; kk++) {
                    bf16x8 vf = *(const bf16x8*)(Vp + kk * 2048 + (f * 16 + l15) * 32 + qs8);
                    oacc[f] = MFMA16(vf, pb[kk], oacc[f]);
                }
        }
        __syncthreads();  // protect buffers before next half's prologue prefetch

        // Epilogue: normalize in-register (l lane-local) -> bf16 AO
        const float inv = 1.0f / lacc[0];
        bf16_t* dst = AO + ((size_t)(b * 2048 + qg)) * 768 + h * 64 + quad * 4;
#pragma unroll
        for (int f = 0; f < 4; f++) {
            bf16x4 o = { (bf16_t)(oacc[f][0] * inv), (bf16_t)(oacc[f][1] * inv),
                         (bf16_t)(oacc[f][2] * inv), (bf16_t)(oacc[f][3] * inv) };
            *(bf16x4*)(dst + f * 16) = o;
        }
    }
}

// ---------------------------------------------------------------------------
extern "C" void kernel_launch(void* const* d_in, const int* in_sizes, int n_in,
                              void* d_out, int out_size, void* d_ws, size_t ws_size,
                              hipStream_t stream)
{
    const float* x    = (const float*)d_in[0];  // [4,2048,768]
    const float* Wqkv = (const float*)d_in[1];  // [768,2304]
    const float* bqkv = (const float*)d_in[2];  // [2304]
    const float* Wo   = (const float*)d_in[3];  // [768,768]
    const float* bo   = (const float*)d_in[4];  // [768]
    float* out = (float*)d_out;                 // [4,2048,768] fp32

    const size_t per = (size_t)48 * 2048 * 64;  // 6291456 bf16 elems
    bf16_t* Qs  = (bf16_t*)d_ws;                // [bh][t][64], pre-scaled
    bf16_t* Kk  = Qs + per;                     // [bh][t][64]
    bf16_t* Vt  = Kk + per;                     // [bh][64][t]
    bf16_t* AO  = Vt + per;                     // [8192,768] bf16
    bf16_t* xb  = AO + per;                     // [8192,768] bf16
    bf16_t* Wt  = xb + per;                     // [2304,768] = Wqkv^T bf16
    bf16_t* Wot = Wt + (size_t)2304 * 768;      // [768,768]  = Wo^T bf16

    // 0) merged precision/layout conversions
    prep_k<<<8448, 256, 0, stream>>>(x, xb, Wqkv, Wt, Wo, Wot);

    // 1) QKV projection; V transposed in-epilogue -> Vt (no vtrans kernel)
    gemm_bt<0><<<18 * 64, 256, 0, stream>>>(
        xb, Wt, bqkv, (void*)Qs, Kk, Vt, 8192, 2304, 768);
    // 2) causal flash attention -> normalized AO (bf16)
    attn_k<<<768, 256, 0, stream>>>(Qs, Kk, Vt, AO);
    // 3) output projection (fp32 out)
    gemm_bt<1><<<6 * 64, 256, 0, stream>>>(
        AO, Wot, bo, (void*)out, nullptr, nullptr, 8192, 768, 768);
}

// Round 14
// 205.456 us; speedup vs baseline: 1.0704x; 1.0118x over previous
//
#include <hip/hip_runtime.h>
#include <hip/hip_bf16.h>

typedef __bf16 bf16_t;
typedef float f32x4 __attribute__((ext_vector_type(4)));
typedef bf16_t bf16x8 __attribute__((ext_vector_type(8)));
typedef bf16_t bf16x4 __attribute__((ext_vector_type(4)));

#define MFMA16(a, b, c) __builtin_amdgcn_mfma_f32_16x16x32_bf16(a, b, c, 0, 0, 0)

// Q pre-scale: 1/sqrt(64) * log2(e), so softmax uses exp2
#define QSCALE 0.18033688011112042f

__device__ __forceinline__ void gl_lds16(const bf16_t* g, bf16_t* l) {
    __builtin_amdgcn_global_load_lds(
        (const __attribute__((address_space(1))) unsigned int*)g,
        (__attribute__((address_space(3))) unsigned int*)l, 16, 0, 0);
}

__device__ __forceinline__ float fexp2(float x) {
    float y;
    asm("v_exp_f32 %0, %1" : "=v"(y) : "v"(x));
    return y;
}

// ---------------------------------------------------------------------------
// Merged prep: [0,6144) x fp32->bf16; [6144,7872) Wqkv^T; [7872,8448) Wo^T.
// ---------------------------------------------------------------------------
__device__ __forceinline__ void conv_t_body(const float* __restrict__ in,
                                            bf16_t* __restrict__ out,
                                            int R, int C, int bx, int by,
                                            float (*t)[33]) {
    const int tx = threadIdx.x & 31;
    const int ty = threadIdx.x >> 5;
#pragma unroll
    for (int i = 0; i < 4; i++)
        t[ty + i * 8][tx] = in[(size_t)(by + ty + i * 8) * C + bx + tx];
    __syncthreads();
#pragma unroll
    for (int i = 0; i < 4; i++)
        out[(size_t)(bx + ty + i * 8) * R + by + tx] = (bf16_t)t[tx][ty + i * 8];
}

__global__ __launch_bounds__(256) void prep_k(
    const float* __restrict__ x,    bf16_t* __restrict__ xb,
    const float* __restrict__ Wqkv, bf16_t* __restrict__ Wt,
    const float* __restrict__ Wo,   bf16_t* __restrict__ Wot)
{
    __shared__ float t[32][33];
    const int blk = blockIdx.x;
    if (blk < 6144) {
        const int i = (blk * 256 + threadIdx.x) * 4;
        float4 v = *(const float4*)(x + i);
        bf16x4 o = { (bf16_t)v.x, (bf16_t)v.y, (bf16_t)v.z, (bf16_t)v.w };
        *(bf16x4*)(xb + i) = o;
    } else if (blk < 7872) {
        const int idx = blk - 6144;
        conv_t_body(Wqkv, Wt, 768, 2304, (idx % 72) * 32, (idx / 72) * 32, t);
    } else {
        const int idx = blk - 7872;
        conv_t_body(Wo, Wot, 768, 768, (idx % 24) * 32, (idx / 24) * 32, t);
    }
}

// ---------------------------------------------------------------------------
// V transpose: Vp [bh][2048][64] -> Vt [bh][64][2048] (R10 version).
// ---------------------------------------------------------------------------
__global__ __launch_bounds__(256) void vtrans(const bf16_t* __restrict__ Vp,
                                              bf16_t* __restrict__ Vt) {
    __shared__ __align__(16) bf16_t Ts[64 * 72];
    const int t0 = blockIdx.x * 64;
    const int bh = blockIdx.y;
    const int r  = threadIdx.x >> 2;
    const int cb = (threadIdx.x & 3) * 16;
    const bf16_t* src = Vp + (((size_t)bh * 2048 + t0 + r) << 6) + cb;
    *(bf16x8*)(Ts + r * 72 + cb)     = *(const bf16x8*)(src);
    *(bf16x8*)(Ts + r * 72 + cb + 8) = *(const bf16x8*)(src + 8);
    __syncthreads();
    const int f  = threadIdx.x >> 2;
    const int tb = (threadIdx.x & 3) * 16;
    bf16_t* dst = Vt + (((size_t)bh * 64 + f) << 11) + t0 + tb;
    bf16x8 a, b;
#pragma unroll
    for (int i = 0; i < 8; i++) a[i] = Ts[(tb + i) * 72 + f];
#pragma unroll
    for (int i = 0; i < 8; i++) b[i] = Ts[(tb + 8 + i) * 72 + f];
    *(bf16x8*)(dst)     = a;
    *(bf16x8*)(dst + 8) = b;
}

// ---------------------------------------------------------------------------
// 128xNT bf16 GEMM (NT = 128 or 64).  BK=32, dbuf, single barrier per
// K-step, XCD swizzle, XOR bank swizzle.  NT=64 halves per-block LDS reads
// AND doubles block count (total LDS traffic unchanged) -> 24 KB LDS ->
// 6 blocks/CU = 24 waves/CU, double R10's residency.  Wave tile 64 x NT/2.
// EPI=0: QKV epilogue, Q/K/V all coalesced [bh][t][64] (V-plain; vtrans
// runs separately — R13's fused version regressed).  EPI=1: fp32 C + bias.
// ---------------------------------------------------------------------------
template <int EPI, int NT>
__global__ __launch_bounds__(256) void gemm_bt(
    const bf16_t* __restrict__ A, const bf16_t* __restrict__ Bt,
    const float* __restrict__ bias,
    void* __restrict__ O0v, bf16_t* __restrict__ O1, bf16_t* __restrict__ O2,
    int M, int N, int K)
{
    constexpr int JN = NT / 32;            // B frags per wave (4 or 2)
    __shared__ __align__(16) bf16_t As[2][128 * 32];
    __shared__ __align__(16) bf16_t Bs[2][NT * 32];

    const int tid  = threadIdx.x;
    const int wid  = tid >> 6;
    const int lane = tid & 63;
    const int quad = lane >> 4;
    const int l15  = lane & 15;
    const int wm   = (wid >> 1) * 64;
    const int wn   = (wid & 1) * (NT / 2);
    const int qs8  = (quad ^ ((l15 >> 1) & 3)) * 8;   // swizzled colblk

    const int mtiles = M >> 7;
    const int mtpx   = mtiles >> 3;
    const int bid    = blockIdx.x;
    const int xcd    = bid & 7;
    const int slot   = bid >> 3;
    const int m0     = (xcd * mtpx + (slot % mtpx)) << 7;
    const int n0     = (slot / mtpx) * NT;

    f32x4 acc[4][JN];
#pragma unroll
    for (int i = 0; i < 4; i++)
#pragma unroll
        for (int j = 0; j < JN; j++) acc[i][j] = (f32x4){0.f, 0.f, 0.f, 0.f};

    const int srow = tid >> 2;
    const int scol = (((tid & 3) ^ ((srow >> 1) & 3))) * 8;   // swizzled src col
    const bf16_t* ag0 = A + (size_t)(m0 + srow) * K + scol;
    const bf16_t* ag1 = A + (size_t)(m0 + 64 + srow) * K + scol;

    auto prefetch = [&](int k0, int buf) {
        gl_lds16(ag0 + k0, As[buf] + tid * 8);
        gl_lds16(ag1 + k0, As[buf] + 2048 + tid * 8);
#pragma unroll
        for (int s = 0; s < NT / 64; s++)
            gl_lds16(Bt + (size_t)(n0 + s * 64 + srow) * K + k0 + scol,
                     Bs[buf] + s * 2048 + tid * 8);
    };

    const int niter = K >> 5;
    prefetch(0, 0);
    for (int i = 0; i < niter; i++) {
        __syncthreads();                   // drains prefetch from iter i-1
        if (i + 1 < niter) prefetch((i + 1) << 5, (i + 1) & 1);
        const bf16_t* Ap = As[i & 1];
        const bf16_t* Bp = Bs[i & 1];

        bf16x8 af[4], bfr[JN];
#pragma unroll
        for (int ii = 0; ii < 4; ii++)
            af[ii] = *(const bf16x8*)(Ap + (wm + ii * 16 + l15) * 32 + qs8);
#pragma unroll
        for (int j = 0; j < JN; j++)
            bfr[j] = *(const bf16x8*)(Bp + (wn + j * 16 + l15) * 32 + qs8);
#pragma unroll
        for (int ii = 0; ii < 4; ii++)
#pragma unroll
            for (int j = 0; j < JN; j++)
                acc[ii][j] = MFMA16(af[ii], bfr[j], acc[ii][j]);
    }

    if (EPI == 0) {
        const int sec = n0 / 768;              // block-uniform (NT | 768-boundaries)
        const float scale = (sec == 0) ? QSCALE : 1.f;
        bf16_t* dst = (sec == 0) ? (bf16_t*)O0v : (sec == 1 ? O1 : O2);
#pragma unroll
        for (int i = 0; i < 4; i++) {
            const int mbase = m0 + wm + i * 16 + quad * 4;
#pragma unroll
            for (int j = 0; j < JN; j++) {
                const int n  = n0 + wn + j * 16 + l15;
                const float bv = bias[n];
                const int d    = n - sec * 768;
                const int h    = d >> 6;
                const int feat = d & 63;
#pragma unroll
                for (int r = 0; r < 4; r++) {
                    const int mm = mbase + r;
                    const int b  = mm >> 11;
                    const int tt = mm & 2047;
                    const int bh = b * 12 + h;
                    dst[(((size_t)bh * 2048 + tt) << 6) + feat] =
                        (bf16_t)((acc[i][j][r] + bv) * scale);
                }
            }
        }
    } else {
#pragma unroll
        for (int i = 0; i < 4; i++) {
            const int mbase = m0 + wm + i * 16 + quad * 4;
#pragma unroll
            for (int j = 0; j < JN; j++) {
                const int n  = n0 + wn + j * 16 + l15;
                const float bv = bias[n];
#pragma unroll
                for (int r = 0; r < 4; r++)
                    ((float*)O0v)[(size_t)(mbase + r) * N + n] = acc[i][j][r] + bv;
            }
        }
    }
}

// ---------------------------------------------------------------------------
// Flash attention — the R10 champion, byte-identical: causal, non-split,
// paired q-tiles (33 KV tiles/block, zero tail), S^T form, dbuf DMA
// staging, XCD swizzle, XOR bank swizzle, lane-local l, direct bf16 AO.
// ---------------------------------------------------------------------------
__global__ __launch_bounds__(256) void attn_k(
    const bf16_t* __restrict__ Q, const bf16_t* __restrict__ Kb,
    const bf16_t* __restrict__ Vt, bf16_t* __restrict__ AO)
{
    __shared__ __align__(16) bf16_t Ks[2 * 4096];   // [buf][kk][kv64][feat32] swz
    __shared__ __align__(16) bf16_t Vs[2 * 4096];   // [buf][kk][feat64][kv32] swz
    __shared__ __align__(16) bf16_t Ps[4 * 1024];

    const int tid  = threadIdx.x;
    const int wid  = tid >> 6;
    const int lane = tid & 63;
    const int quad = lane >> 4;
    const int l15  = lane & 15;
    const int qs8  = (quad ^ ((l15 >> 1) & 3)) * 8;

    const int bid  = blockIdx.x;
    const int xcd  = bid & 7;
    const int slot = bid >> 3;
    const int bh   = xcd * 6 + (slot >> 4);
    const int p    = slot & 15;

    const bf16_t* Qb  = Q  + ((size_t)bh << 17);
    const bf16_t* Kbh = Kb + ((size_t)bh << 17);
    const bf16_t* Vbh = Vt + ((size_t)bh << 17);

    bf16_t* Pw = Ps + wid * 1024;
    const int swl = l15 & 7;
    bf16_t* pwr[4];
#pragma unroll
    for (int c = 0; c < 4; c++)
        pwr[c] = Pw + l15 * 64 + (((((c << 1) | (quad >> 1))) ^ swl) << 3) + ((quad & 1) << 2);
    const bf16_t* prd[2];
#pragma unroll
    for (int kk = 0; kk < 2; kk++)
        prd[kk] = Pw + l15 * 64 + ((((kk << 2) | quad) ^ swl) << 3);

    const bf16x8 ones = { (bf16_t)1.f, (bf16_t)1.f, (bf16_t)1.f, (bf16_t)1.f,
                          (bf16_t)1.f, (bf16_t)1.f, (bf16_t)1.f, (bf16_t)1.f };

    const int srow = tid >> 2;
    const int scol = (((tid & 3) ^ ((srow >> 1) & 3))) * 8;

    auto prefetch = [&](int j, int buf) {
        const int kv0 = j * 64;
        bf16_t* kd = Ks + buf * 4096 + tid * 8;
        bf16_t* vd = Vs + buf * 4096 + tid * 8;
#pragma unroll
        for (int c = 0; c < 2; c++) {
            gl_lds16(Kbh + (size_t)(kv0 + srow) * 64 + c * 32 + scol, kd + c * 2048);
            gl_lds16(Vbh + (size_t)srow * 2048 + kv0 + c * 32 + scol, vd + c * 2048);
        }
    };

    const int b = bh / 12;
    const int h = bh - b * 12;

#pragma unroll
    for (int half = 0; half < 2; half++) {
        const int qt = half == 0 ? (31 - p) : p;
        const int q0 = qt * 64;
        const int qg = q0 + wid * 16 + l15;

        bf16x8 qf[2];
        {
            const bf16_t* qp = Qb + ((size_t)qg << 6) + quad * 8;
            qf[0] = *(const bf16x8*)(qp);
            qf[1] = *(const bf16x8*)(qp + 32);
        }

        f32x4 lacc = (f32x4){0.f, 0.f, 0.f, 0.f};
        f32x4 oacc[4];
#pragma unroll
        for (int f = 0; f < 4; f++) oacc[f] = (f32x4){0.f, 0.f, 0.f, 0.f};

        const int cnt = qt + 1;
        prefetch(0, 0);

        for (int i = 0; i < cnt; i++) {
            __syncthreads();                   // drains prefetch from iter i-1
            if (i + 1 < cnt) prefetch(i + 1, (i + 1) & 1);
            const bf16_t* Kp = Ks + (i & 1) * 4096;
            const bf16_t* Vp = Vs + (i & 1) * 4096;

            f32x4 st[4];
#pragma unroll
            for (int c = 0; c < 4; c++) {
                st[c] = (f32x4){0.f, 0.f, 0.f, 0.f};
#pragma unroll
                for (int kk = 0; kk < 2; kk++) {
                    bf16x8 kf = *(const bf16x8*)(Kp + kk * 2048 + (c * 16 + l15) * 32 + qs8);
                    st[c] = MFMA16(kf, qf[kk], st[c]);
                }
            }

            if (i == qt) {
                const int kvb = q0 + quad * 4;
#pragma unroll
                for (int c = 0; c < 4; c++)
#pragma unroll
                    for (int r = 0; r < 4; r++)
                        if (kvb + c * 16 + r > qg) st[c][r] = -3e38f;
            }

#pragma unroll
            for (int c = 0; c < 4; c++) {
                bf16x4 pk = { (bf16_t)fexp2(st[c][0]), (bf16_t)fexp2(st[c][1]),
                              (bf16_t)fexp2(st[c][2]), (bf16_t)fexp2(st[c][3]) };
                *(bf16x4*)pwr[c] = pk;
            }

            bf16x8 pb[2];
#pragma unroll
            for (int kk = 0; kk < 2; kk++)
                pb[kk] = *(const bf16x8*)prd[kk];

            lacc = MFMA16(ones, pb[0], lacc);
            lacc = MFMA16(ones, pb[1], lacc);

#pragma unroll
            for (int f = 0; f < 4; f++)
#pragma unroll
                for (int kk = 0; kk < 2; kk++) {
                    bf16x8 vf = *(const bf16x8*)(Vp + kk * 2048 + (f * 16 + l15) * 32 + qs8);
                    oacc[f] = MFMA16(vf, pb[kk], oacc[f]);
                }
        }
        __syncthreads();  // protect buffers before next half's prologue prefetch

        const float inv = 1.0f / lacc[0];
        bf16_t* dst = AO + ((size_t)(b * 2048 + qg)) * 768 + h * 64 + quad * 4;
#pragma unroll
        for (int f = 0; f < 4; f++) {
            bf16x4 o = { (bf16_t)(oacc[f][0] * inv), (bf16_t)(oacc[f][1] * inv),
                         (bf16_t)(oacc[f][2] * inv), (bf16_t)(oacc[f][3] * inv) };
            *(bf16x4*)(dst + f * 16) = o;
        }
    }
}

// ---------------------------------------------------------------------------
extern "C" void kernel_launch(void* const* d_in, const int* in_sizes, int n_in,
                              void* d_out, int out_size, void* d_ws, size_t ws_size,
                              hipStream_t stream)
{
    const float* x    = (const float*)d_in[0];  // [4,2048,768]
    const float* Wqkv = (const float*)d_in[1];  // [768,2304]
    const float* bqkv = (const float*)d_in[2];  // [2304]
    const float* Wo   = (const float*)d_in[3];  // [768,768]
    const float* bo   = (const float*)d_in[4];  // [768]
    float* out = (float*)d_out;                 // [4,2048,768] fp32

    const size_t per = (size_t)48 * 2048 * 64;  // 6291456 bf16 elems
    bf16_t* Qs  = (bf16_t*)d_ws;                // [bh][t][64], pre-scaled
    bf16_t* Kk  = Qs + per;                     // [bh][t][64]
    bf16_t* Vt  = Kk + per;                     // [bh][64][t]
    bf16_t* AO  = Vt + per;                     // [8192,768] bf16
    bf16_t* xb  = AO + per;                     // [8192,768] bf16
    bf16_t* Wt  = xb + per;                     // [2304,768] = Wqkv^T bf16
    bf16_t* Wot = Wt + (size_t)2304 * 768;      // [768,768]  = Wo^T bf16
    bf16_t* Vpl = (bf16_t*)d_out;               // V plain parked in out

    // 0) merged precision/layout conversions
    prep_k<<<8448, 256, 0, stream>>>(x, xb, Wqkv, Wt, Wo, Wot);

    // 1) QKV projection, NT=64 (2304 blocks, 6/CU)
    gemm_bt<0, 64><<<36 * 64, 256, 0, stream>>>(
        xb, Wt, bqkv, (void*)Qs, Kk, Vpl, 8192, 2304, 768);
    // 1b) V transpose -> Vt [bh][64][t]
    vtrans<<<dim3(32, 48), 256, 0, stream>>>(Vpl, Vt);
    // 2) causal flash attention (R10 champion) -> normalized AO
    attn_k<<<768, 256, 0, stream>>>(Qs, Kk, Vt, AO);
    // 3) output projection, NT=64 (768 blocks, 6/CU)
    gemm_bt<1, 64><<<12 * 64, 256, 0, stream>>>(
        AO, Wot, bo, (void*)out, nullptr, nullptr, 8192, 768, 768);
}